// Round 3
// baseline (398.765 us; speedup 1.0000x reference)
//
#include <hip/hip_runtime.h>
#include <stdint.h>

typedef __bf16 bf16;
typedef __bf16 bf16x8 __attribute__((ext_vector_type(8)));  // 16B, alignof 16
typedef __bf16 bf16x4 __attribute__((ext_vector_type(4)));  // 8B
typedef float  f32x4  __attribute__((ext_vector_type(4)));

#define MFMA_BF16(a, b, c) __builtin_amdgcn_mfma_f32_16x16x32_bf16((a), (b), (c), 0, 0, 0)

static constexpr int BATCH = 2;
static constexpr int SEQ   = 2048;
static constexpr int DIM   = 1024;
static constexpr int HDIM  = 64;
static constexpr int MROWS = BATCH * SEQ;   // 4096
static constexpr int NIN   = 11;

// converted-input element offsets within the conv region (dict order)
static const long long H_OFF[NIN] = {
    0, 4194304, 8388608,                 // q, k, v
    12582912, 13631488,                  // Wq, bq
    13632512, 14681088,                  // Wk, bk
    14682112, 15730688,                  // Wv, bv
    15731712, 16780288                   // Wo, bo
};
static constexpr long long CONV_TOTAL = 16781312;

struct InPack {
    const void* p[NIN];
    long long   o[NIN];
    int         n[NIN];
};

__device__ __forceinline__ float scrubf(float v) {
    unsigned b = __float_as_uint(v);
    return ((b & 0x7f800000u) == 0x7f800000u) ? 0.f : v;  // NaN/Inf -> 0
}

// ---------------------------------------------------------------------------
// Per-input dtype detection. Interpret leading words as bf16; count elements
// with exponent >= 0x89 (|x| >= 1024, incl. inf/nan). True bf16 data here has
// |x| <= ~5 -> count 0. fp32 data misread as bf16 -> ~46% of low-half words
// are "bad". flags[i] = 1 means "buffer i is fp32".
// ---------------------------------------------------------------------------
__global__ void detect_kernel(InPack in, int* __restrict__ flags) {
    const int i = blockIdx.x;
    const unsigned short* s = (const unsigned short*)in.p[i];
    const int scan = in.n[i] < 65536 ? in.n[i] : 65536;
    __shared__ int bad;
    if (threadIdx.x == 0) bad = 0;
    __syncthreads();
    int local = 0;
    for (int j = threadIdx.x; j < scan; j += 256) {
        const int e = (s[j] >> 7) & 0xFF;
        if (e >= 0x89) ++local;
    }
    if (local) atomicAdd(&bad, local);
    __syncthreads();
    if (threadIdx.x == 0) flags[i] = (bad > 0) ? 1 : 0;
}

// ---------------------------------------------------------------------------
// Convert every input to clean bf16 in ws (scrub non-finite), per its flag.
// ---------------------------------------------------------------------------
__global__ void convert_kernel(InPack in, bf16* __restrict__ dstbase,
                               const int* __restrict__ flags) {
    const int i = blockIdx.y;
    const int n = in.n[i];
    bf16* dst = dstbase + in.o[i];
    const bool isf32 = (flags[i] != 0);
    for (int j = blockIdx.x * 256 + threadIdx.x; j < n; j += gridDim.x * 256) {
        float v;
        if (isf32) {
            v = ((const float*)in.p[i])[j];
        } else {
            const unsigned short u = ((const unsigned short*)in.p[i])[j];
            v = __uint_as_float(((unsigned)u) << 16);
        }
        dst[j] = (bf16)scrubf(v);
    }
}

// ---------------------------------------------------------------------------
// Write final output in the dtype matching the query buffer's detected dtype.
// ---------------------------------------------------------------------------
__global__ void writeback_kernel(const bf16* __restrict__ src, void* __restrict__ out,
                                 const int* __restrict__ flags, int n) {
    const bool f32 = (flags[0] != 0);
    for (int j = blockIdx.x * 256 + threadIdx.x; j < n; j += gridDim.x * 256) {
        if (f32) ((float*)out)[j] = (float)src[j];
        else     ((bf16*)out)[j]  = src[j];
    }
}

// ---------------------------------------------------------------------------
// GEMM: C[M, DIM] = A[M, DIM] @ W[DIM, DIM]^T + bias   (W row-major [out,in])
// 128x128 tile, BK=32, 256 threads = 4 waves in 2x2, each wave owns 64x64.
// ---------------------------------------------------------------------------
__global__ __launch_bounds__(256, 2) void gemm_bt_kernel(
    const bf16* __restrict__ A0, const bf16* __restrict__ W0,
    const bf16* __restrict__ b0, bf16* __restrict__ C0,
    const bf16* __restrict__ A1, const bf16* __restrict__ W1,
    const bf16* __restrict__ b1, bf16* __restrict__ C1,
    const bf16* __restrict__ A2, const bf16* __restrict__ W2,
    const bf16* __restrict__ b2, bf16* __restrict__ C2)
{
    const int z = blockIdx.z;
    const bf16* A    = (z == 0) ? A0 : (z == 1) ? A1 : A2;
    const bf16* W    = (z == 0) ? W0 : (z == 1) ? W1 : W2;
    const bf16* bias = (z == 0) ? b0 : (z == 1) ? b1 : b2;
    bf16*       C    = (z == 0) ? C0 : (z == 1) ? C1 : C2;

    const int n0 = blockIdx.x * 128;
    const int m0 = blockIdx.y * 128;

    __shared__ bf16 As[128][40];
    __shared__ bf16 Bs[128][40];

    const int t    = threadIdx.x;
    const int w    = t >> 6;
    const int ln   = t & 15;
    const int quad = (t >> 4) & 3;
    const int wm   = (w & 1) * 64;
    const int wn   = (w >> 1) * 64;

    const int srow = t >> 2;
    const int scol = (t & 3) * 8;

    f32x4 acc[4][4];
#pragma unroll
    for (int i = 0; i < 4; ++i)
#pragma unroll
        for (int j = 0; j < 4; ++j) acc[i][j] = (f32x4){0.f, 0.f, 0.f, 0.f};

    for (int k0 = 0; k0 < DIM; k0 += 32) {
        __syncthreads();
        *(bf16x8*)&As[srow][scol]      = *(const bf16x8*)(A + (size_t)(m0 + srow) * DIM + k0 + scol);
        *(bf16x8*)&As[64 + srow][scol] = *(const bf16x8*)(A + (size_t)(m0 + 64 + srow) * DIM + k0 + scol);
        *(bf16x8*)&Bs[srow][scol]      = *(const bf16x8*)(W + (size_t)(n0 + srow) * DIM + k0 + scol);
        *(bf16x8*)&Bs[64 + srow][scol] = *(const bf16x8*)(W + (size_t)(n0 + 64 + srow) * DIM + k0 + scol);
        __syncthreads();

        bf16x8 af[4], bfr[4];
#pragma unroll
        for (int mt = 0; mt < 4; ++mt)
            af[mt] = *(const bf16x8*)&As[wm + mt * 16 + ln][quad * 8];
#pragma unroll
        for (int nt = 0; nt < 4; ++nt)
            bfr[nt] = *(const bf16x8*)&Bs[wn + nt * 16 + ln][quad * 8];
#pragma unroll
        for (int mt = 0; mt < 4; ++mt)
#pragma unroll
            for (int nt = 0; nt < 4; ++nt)
                acc[mt][nt] = MFMA_BF16(af[mt], bfr[nt], acc[mt][nt]);
    }

#pragma unroll
    for (int nt = 0; nt < 4; ++nt) {
        const int col  = n0 + wn + nt * 16 + ln;
        const float bv = (float)bias[col];
#pragma unroll
        for (int mt = 0; mt < 4; ++mt)
#pragma unroll
            for (int r = 0; r < 4; ++r) {
                const int row = m0 + wm + mt * 16 + quad * 4 + r;
                C[(size_t)row * DIM + col] = (bf16)(acc[mt][nt][r] + bv);
            }
    }
}

// ---------------------------------------------------------------------------
// Flash attention: block = 64 q-rows of one (b,h); 128-row K/V tiles, online
// softmax; quad-group shuffle reduction; P via LDS C->A layout transform.
// ---------------------------------------------------------------------------
__global__ __launch_bounds__(256, 2) void attn_kernel(
    const bf16* __restrict__ Q, const bf16* __restrict__ K,
    const bf16* __restrict__ V, bf16* __restrict__ O)
{
    const int qt = blockIdx.x;
    const int bh = blockIdx.y;
    const int b  = bh >> 4;
    const int h  = bh & 15;

    __shared__ bf16 Ks[128][72];
    __shared__ bf16 Vt[64][136];
    __shared__ bf16 Ps[64][136];

    const int t    = threadIdx.x;
    const int w    = t >> 6;
    const int ln   = t & 15;
    const int quad = (t >> 4) & 3;

    const int q0 = qt * 64;

    const bf16* qrow = Q + (size_t)(b * SEQ + q0 + w * 16 + ln) * DIM + h * HDIM;
    const bf16x8 qf0 = *(const bf16x8*)(qrow + quad * 8);
    const bf16x8 qf1 = *(const bf16x8*)(qrow + 32 + quad * 8);

    f32x4 o_acc[4];
#pragma unroll
    for (int c = 0; c < 4; ++c) o_acc[c] = (f32x4){0.f, 0.f, 0.f, 0.f};
    float m_s[4] = {-1e30f, -1e30f, -1e30f, -1e30f};
    float l_s[4] = {0.f, 0.f, 0.f, 0.f};

    const float sc = 0.125f * 1.44269504089f;

    const int krow = t >> 3;
    const int kcol = (t & 7) * 8;
    const int vrq  = t >> 3;
    const int vcc  = (t & 7) * 8;

    for (int kb = 0; kb < SEQ; kb += 128) {
        __syncthreads();
#pragma unroll
        for (int i = 0; i < 4; ++i) {
            const int r = krow + i * 32;
            *(bf16x8*)&Ks[r][kcol] =
                *(const bf16x8*)(K + (size_t)(b * SEQ + kb + r) * DIM + h * HDIM + kcol);
        }
        {
            bf16x8 vrow[4];
            const bf16* vbase = V + (size_t)(b * SEQ + kb + vrq * 4) * DIM + h * HDIM + vcc;
#pragma unroll
            for (int i = 0; i < 4; ++i)
                vrow[i] = *(const bf16x8*)(vbase + (size_t)i * DIM);
#pragma unroll
            for (int j = 0; j < 8; ++j) {
                bf16x4 pk = {vrow[0][j], vrow[1][j], vrow[2][j], vrow[3][j]};
                *(bf16x4*)&Vt[vcc + j][vrq * 4] = pk;
            }
        }
        __syncthreads();

        f32x4 sa[8];
#pragma unroll
        for (int nt = 0; nt < 8; ++nt) {
            const bf16x8 kf0 = *(const bf16x8*)&Ks[nt * 16 + ln][quad * 8];
            const bf16x8 kf1 = *(const bf16x8*)&Ks[nt * 16 + ln][32 + quad * 8];
            f32x4 zz = (f32x4){0.f, 0.f, 0.f, 0.f};
            zz = MFMA_BF16(qf0, kf0, zz);
            zz = MFMA_BF16(qf1, kf1, zz);
            sa[nt] = zz;
        }

#pragma unroll
        for (int r = 0; r < 4; ++r) {
            float mx = -1e30f;
#pragma unroll
            for (int nt = 0; nt < 8; ++nt) {
                sa[nt][r] *= sc;
                mx = fmaxf(mx, sa[nt][r]);
            }
            mx = fmaxf(mx, __shfl_xor(mx, 1));
            mx = fmaxf(mx, __shfl_xor(mx, 2));
            mx = fmaxf(mx, __shfl_xor(mx, 4));
            mx = fmaxf(mx, __shfl_xor(mx, 8));
            const float mn = fmaxf(m_s[r], mx);
            const float al = exp2f(m_s[r] - mn);
            m_s[r] = mn;
            float rs = 0.f;
#pragma unroll
            for (int nt = 0; nt < 8; ++nt) {
                const float p = exp2f(sa[nt][r] - mn);
                sa[nt][r] = p;
                rs += p;
            }
            rs += __shfl_xor(rs, 1);
            rs += __shfl_xor(rs, 2);
            rs += __shfl_xor(rs, 4);
            rs += __shfl_xor(rs, 8);
            l_s[r] = l_s[r] * al + rs;
#pragma unroll
            for (int c = 0; c < 4; ++c) o_acc[c][r] *= al;
        }

#pragma unroll
        for (int nt = 0; nt < 8; ++nt)
#pragma unroll
            for (int r = 0; r < 4; ++r)
                Ps[w * 16 + quad * 4 + r][nt * 16 + ln] = (bf16)sa[nt][r];

        __syncthreads();

#pragma unroll
        for (int kc = 0; kc < 4; ++kc) {
            const bf16x8 pf = *(const bf16x8*)&Ps[w * 16 + ln][kc * 32 + quad * 8];
#pragma unroll
            for (int c = 0; c < 4; ++c) {
                const bf16x8 vf = *(const bf16x8*)&Vt[c * 16 + ln][kc * 32 + quad * 8];
                o_acc[c] = MFMA_BF16(pf, vf, o_acc[c]);
            }
        }
    }

#pragma unroll
    for (int r = 0; r < 4; ++r) {
        const float inv = 1.0f / l_s[r];
        const size_t rowoff = (size_t)(b * SEQ + q0 + w * 16 + quad * 4 + r) * DIM + h * HDIM;
#pragma unroll
        for (int c = 0; c < 4; ++c)
            O[rowoff + c * 16 + ln] = (bf16)(o_acc[c][r] * inv);
    }
}

extern "C" void kernel_launch(void* const* d_in, const int* in_sizes, int n_in,
                              void* d_out, int out_size, void* d_ws, size_t ws_size,
                              hipStream_t stream) {
    // ws layout (bf16 elements):
    //   Qb, Kb, Vb, Ob, OutB: 5 x 4,194,304
    //   conv inputs: CONV_TOTAL elements at offset 20,971,520
    //   flags: int[11] after that
    bf16* Qb   = (bf16*)d_ws;
    bf16* Kb   = Qb + (size_t)MROWS * DIM;
    bf16* Vb   = Kb + (size_t)MROWS * DIM;
    bf16* Ob   = Vb + (size_t)MROWS * DIM;
    bf16* OutB = Ob + (size_t)MROWS * DIM;
    bf16* conv = OutB + (size_t)MROWS * DIM;
    int*  flags = (int*)(conv + CONV_TOTAL);

    InPack pack;
    for (int i = 0; i < NIN; ++i) {
        pack.p[i] = d_in[i];
        pack.o[i] = H_OFF[i];
        pack.n[i] = in_sizes[i];
    }

    detect_kernel<<<NIN, 256, 0, stream>>>(pack, flags);
    convert_kernel<<<dim3(512, NIN), 256, 0, stream>>>(pack, conv, flags);

    const bf16* qc  = conv + H_OFF[0];
    const bf16* kc  = conv + H_OFF[1];
    const bf16* vc  = conv + H_OFF[2];
    const bf16* Wqc = conv + H_OFF[3];
    const bf16* bqc = conv + H_OFF[4];
    const bf16* Wkc = conv + H_OFF[5];
    const bf16* bkc = conv + H_OFF[6];
    const bf16* Wvc = conv + H_OFF[7];
    const bf16* bvc = conv + H_OFF[8];
    const bf16* Woc = conv + H_OFF[9];
    const bf16* boc = conv + H_OFF[10];

    gemm_bt_kernel<<<dim3(DIM / 128, MROWS / 128, 3), 256, 0, stream>>>(
        qc, Wqc, bqc, Qb,  kc, Wkc, bkc, Kb,  vc, Wvc, bvc, Vb);

    attn_kernel<<<dim3(SEQ / 64, BATCH * 16), 256, 0, stream>>>(Qb, Kb, Vb, Ob);

    gemm_bt_kernel<<<dim3(DIM / 128, MROWS / 128, 1), 256, 0, stream>>>(
        Ob, Woc, boc, OutB,  Ob, Woc, boc, OutB,  Ob, Woc, boc, OutB);

    writeback_kernel<<<1024, 256, 0, stream>>>(OutB, d_out, flags, out_size);
}

// Round 4
// 333.447 us; speedup vs baseline: 1.1959x; 1.1959x over previous
//
#include <hip/hip_runtime.h>
#include <stdint.h>

typedef __bf16 bf16;
typedef __bf16 bf16x8 __attribute__((ext_vector_type(8)));  // 16B
typedef __bf16 bf16x4 __attribute__((ext_vector_type(4)));  // 8B
typedef float  f32x4  __attribute__((ext_vector_type(4)));

#define MFMA_BF16(a, b, c) __builtin_amdgcn_mfma_f32_16x16x32_bf16((a), (b), (c), 0, 0, 0)

static constexpr int BATCH = 2;
static constexpr int SEQ   = 2048;
static constexpr int DIM   = 1024;
static constexpr int HDIM  = 64;
static constexpr int MROWS = BATCH * SEQ;   // 4096
static constexpr int NIN   = 11;

static const long long H_OFF[NIN] = {
    0, 4194304, 8388608,                 // q, k, v
    12582912, 13631488,                  // Wq, bq
    13632512, 14681088,                  // Wk, bk
    14682112, 15730688,                  // Wv, bv
    15731712, 16780288                   // Wo, bo
};
static constexpr long long CONV_TOTAL = 16781312;

struct InPack {
    const void* p[NIN];
    long long   o[NIN];
    int         n[NIN];
};

__device__ __forceinline__ float scrubf(float v) {
    unsigned b = __float_as_uint(v);
    return ((b & 0x7f800000u) == 0x7f800000u) ? 0.f : v;  // NaN/Inf -> 0
}

typedef const __attribute__((address_space(1))) void* gvp;
typedef __attribute__((address_space(3))) void* svp;
__device__ __forceinline__ void glds16(const bf16* g, bf16* l) {
    // async global->LDS, 16B/lane; LDS dest = wave-uniform base + lane*16
    __builtin_amdgcn_global_load_lds((gvp)(const void*)g, (svp)(void*)l, 16, 0, 0);
}

// ---------------------------------------------------------------------------
// dtype detection (fp32 vs bf16), per input buffer. flags[i]=1 -> fp32.
// ---------------------------------------------------------------------------
__global__ void detect_kernel(InPack in, int* __restrict__ flags) {
    const int i = blockIdx.x;
    const unsigned short* s = (const unsigned short*)in.p[i];
    const int scan = in.n[i] < 65536 ? in.n[i] : 65536;
    __shared__ int bad;
    if (threadIdx.x == 0) bad = 0;
    __syncthreads();
    int local = 0;
    for (int j = threadIdx.x; j < scan; j += 256) {
        const int e = (s[j] >> 7) & 0xFF;
        if (e >= 0x89) ++local;   // |x|>=1024 or inf/nan: impossible for true bf16 here
    }
    if (local) atomicAdd(&bad, local);
    __syncthreads();
    if (threadIdx.x == 0) flags[i] = (bad > 0) ? 1 : 0;
}

// ---------------------------------------------------------------------------
// Convert inputs to clean bf16 (x4 vectorized; all sizes divisible by 4).
// ---------------------------------------------------------------------------
__global__ void convert_kernel(InPack in, bf16* __restrict__ dstbase,
                               const int* __restrict__ flags) {
    const int i = blockIdx.y;
    const int n4 = in.n[i] >> 2;
    bf16* dst = dstbase + in.o[i];
    const bool isf32 = (flags[i] != 0);
    for (int j = blockIdx.x * 256 + threadIdx.x; j < n4; j += gridDim.x * 256) {
        float v0, v1, v2, v3;
        if (isf32) {
            const float4 f = ((const float4*)in.p[i])[j];
            v0 = f.x; v1 = f.y; v2 = f.z; v3 = f.w;
        } else {
            const ushort4 u = ((const ushort4*)in.p[i])[j];
            v0 = __uint_as_float((unsigned)u.x << 16);
            v1 = __uint_as_float((unsigned)u.y << 16);
            v2 = __uint_as_float((unsigned)u.z << 16);
            v3 = __uint_as_float((unsigned)u.w << 16);
        }
        bf16x4 o = {(bf16)scrubf(v0), (bf16)scrubf(v1), (bf16)scrubf(v2), (bf16)scrubf(v3)};
        *(bf16x4*)&dst[(size_t)j * 4] = o;
    }
}

__global__ void writeback_kernel(const bf16* __restrict__ src, void* __restrict__ out,
                                 const int* __restrict__ flags, int n) {
    const bool f32 = (flags[0] != 0);
    const int n4 = n >> 2;
    for (int j = blockIdx.x * 256 + threadIdx.x; j < n4; j += gridDim.x * 256) {
        const bf16x4 s = *(const bf16x4*)&src[(size_t)j * 4];
        if (f32) {
            float4 f = {(float)s[0], (float)s[1], (float)s[2], (float)s[3]};
            ((float4*)out)[j] = f;
        } else {
            ((bf16x4*)out)[j] = s;
        }
    }
}

// ---------------------------------------------------------------------------
// GEMM: C[M,DIM] = A[M,DIM] @ W[DIM,DIM]^T + bias. 128x128 tile, BK=32,
// m97-style global_load_lds(16B) staging into unpadded [row][32] LDS
// (64B row stride -> frag reads are conflict-free: bank = 16*(row&1)+4*quad).
// ---------------------------------------------------------------------------
__global__ __launch_bounds__(256, 3) void gemm_bt_kernel(
    const bf16* __restrict__ A0, const bf16* __restrict__ W0,
    const bf16* __restrict__ b0, bf16* __restrict__ C0,
    const bf16* __restrict__ A1, const bf16* __restrict__ W1,
    const bf16* __restrict__ b1, bf16* __restrict__ C1,
    const bf16* __restrict__ A2, const bf16* __restrict__ W2,
    const bf16* __restrict__ b2, bf16* __restrict__ C2)
{
    const int z = blockIdx.z;
    const bf16* A    = (z == 0) ? A0 : (z == 1) ? A1 : A2;
    const bf16* W    = (z == 0) ? W0 : (z == 1) ? W1 : W2;
    const bf16* bias = (z == 0) ? b0 : (z == 1) ? b1 : b2;
    bf16*       C    = (z == 0) ? C0 : (z == 1) ? C1 : C2;

    const int n0 = blockIdx.x * 128;
    const int m0 = blockIdx.y * 128;

    __shared__ bf16 As[128 * 32];
    __shared__ bf16 Bs[128 * 32];

    const int t    = threadIdx.x;
    const int w    = t >> 6;
    const int lane = t & 63;
    const int ln   = t & 15;
    const int quad = (t >> 4) & 3;
    const int wm   = (w & 1) * 64;
    const int wn   = (w >> 1) * 64;

    // staging: wave w stages rows [w*32, w*32+32) of both tiles, 2 instr each.
    // lane l -> row w*32 (+16) + (l>>2), elements (l&3)*8.
    const int srow = w * 32 + (lane >> 2);
    const int scol = (lane & 3) * 8;
    const bf16* gA = A + (size_t)(m0 + srow) * DIM + scol;
    const bf16* gB = W + (size_t)(n0 + srow) * DIM + scol;
    bf16* lA = &As[w * 32 * 32];     // wave-uniform LDS bases
    bf16* lB = &Bs[w * 32 * 32];

    f32x4 acc[4][4];
#pragma unroll
    for (int i = 0; i < 4; ++i)
#pragma unroll
        for (int j = 0; j < 4; ++j) acc[i][j] = (f32x4){0.f, 0.f, 0.f, 0.f};

    for (int k0 = 0; k0 < DIM; k0 += 32) {
        __syncthreads();
        glds16(gA + k0,            lA);
        glds16(gA + 16 * DIM + k0, lA + 16 * 32);
        glds16(gB + k0,            lB);
        glds16(gB + 16 * DIM + k0, lB + 16 * 32);
        __syncthreads();   // drains vmcnt: staged data visible block-wide

        bf16x8 af[4], bfr[4];
#pragma unroll
        for (int mt = 0; mt < 4; ++mt)
            af[mt] = *(const bf16x8*)&As[(wm + mt * 16 + ln) * 32 + quad * 8];
#pragma unroll
        for (int nt = 0; nt < 4; ++nt)
            bfr[nt] = *(const bf16x8*)&Bs[(wn + nt * 16 + ln) * 32 + quad * 8];
#pragma unroll
        for (int mt = 0; mt < 4; ++mt)
#pragma unroll
            for (int nt = 0; nt < 4; ++nt)
                acc[mt][nt] = MFMA_BF16(af[mt], bfr[nt], acc[mt][nt]);
    }

    // epilogue: bias + bf16 store (C/D: row = quad*4+reg, col = ln)
#pragma unroll
    for (int nt = 0; nt < 4; ++nt) {
        const int col  = n0 + wn + nt * 16 + ln;
        const float bv = (float)bias[col];
#pragma unroll
        for (int mt = 0; mt < 4; ++mt)
#pragma unroll
            for (int r = 0; r < 4; ++r) {
                const int row = m0 + wm + mt * 16 + quad * 4 + r;
                C[(size_t)row * DIM + col] = (bf16)(acc[mt][nt][r] + bv);
            }
    }
}

// ---------------------------------------------------------------------------
// Flash attention, S^T formulation: per K-tile compute S^T = K_tile · Q^T
// (A=K rows, B=Q^T). C-layout then puts, in each lane: q = lane&15 (one
// column), k = nt*16 + quad*4 + reg -> 4 CONSECUTIVE k per frag:
//  - softmax state is one scalar per lane; quad-combine via shfl_xor 16/32
//  - P-writes are 8 vectorized conflict-free ds_write_b64 (was 32 scalar)
//  - Ps rows are wave-private -> no barrier, just s_waitcnt lgkmcnt(0)
// V^T staged with XOR-chunk swizzle: phys_chunk = log_chunk ^ (e>>3) keeps
// both the transpose b64 writes and b128 B-frag reads conflict-free.
// ---------------------------------------------------------------------------
__global__ __launch_bounds__(256, 3) void attn_kernel(
    const bf16* __restrict__ Q, const bf16* __restrict__ K,
    const bf16* __restrict__ V, bf16* __restrict__ O)
{
    const int qt = blockIdx.x;        // 0..31: 64 q-rows
    const int bh = blockIdx.y;        // 0..31
    const int b  = bh >> 4;
    const int h  = bh & 15;

    __shared__ bf16 Ks[128 * 72];     // [k_row][e], stride 72 (144B)
    __shared__ bf16 Vt[64 * 136];     // [e][k], stride 136 (272B), chunk-swizzled
    __shared__ bf16 Ps[64 * 136];     // [q][k],  stride 136

    const int t    = threadIdx.x;
    const int w    = t >> 6;
    const int lane = t & 63;
    const int ln   = lane & 15;
    const int quad = lane >> 4;

    const int q0 = qt * 64;

    // Q^T B-operand frags, pre-scaled by 1/sqrt(HD)*log2(e) (once per block)
    const float sc = 0.125f * 1.44269504089f;
    const bf16* qrow = Q + (size_t)(b * SEQ + q0 + w * 16 + ln) * DIM + h * HDIM;
    bf16x8 qf0 = *(const bf16x8*)(qrow + quad * 8);
    bf16x8 qf1 = *(const bf16x8*)(qrow + 32 + quad * 8);
#pragma unroll
    for (int i = 0; i < 8; ++i) {
        qf0[i] = (bf16)((float)qf0[i] * sc);
        qf1[i] = (bf16)((float)qf1[i] * sc);
    }

    f32x4 o_acc[4];
#pragma unroll
    for (int c = 0; c < 4; ++c) o_acc[c] = (f32x4){0.f, 0.f, 0.f, 0.f};
    float m_s = -1e30f, l_s = 0.f;

    const int krow = t >> 3;          // 0..31: K staging (4 rows each, +i*32)
    const int kcol = (t & 7) * 8;
    const int vrq  = t >> 3;          // 0..31: V rows vrq*4..+3
    const int va   = t & 7;           // e-octet: e = va*8 + j  (e>>3 == va)
    const int psrow = (w * 16 + ln) * 136;

    for (int kb = 0; kb < SEQ; kb += 128) {
        __syncthreads();              // prev-iter Ks/Vt reads complete
        // ---- stage K [128][64]
#pragma unroll
        for (int i = 0; i < 4; ++i) {
            const int r = krow + i * 32;
            *(bf16x8*)&Ks[r * 72 + kcol] =
                *(const bf16x8*)(K + (size_t)(b * SEQ + kb + r) * DIM + h * HDIM + kcol);
        }
        // ---- stage V^T with XOR-chunk swizzle (conflict-free b64 writes)
        {
            bf16x8 vrow[4];
            const bf16* vbase = V + (size_t)(b * SEQ + kb + vrq * 4) * DIM + h * HDIM + va * 8;
#pragma unroll
            for (int i = 0; i < 4; ++i)
                vrow[i] = *(const bf16x8*)(vbase + (size_t)i * DIM);
            const int phys = ((vrq >> 1) ^ va) * 8 + (vrq & 1) * 4;
#pragma unroll
            for (int j = 0; j < 8; ++j) {
                bf16x4 pk = {vrow[0][j], vrow[1][j], vrow[2][j], vrow[3][j]};
                *(bf16x4*)&Vt[(va * 8 + j) * 136 + phys] = pk;
            }
        }
        __syncthreads();

        // ---- S^T = K·Q^T : lane holds q = w*16+ln; k = nt*16 + quad*4 + r
        f32x4 sa[8];
#pragma unroll
        for (int nt = 0; nt < 8; ++nt) {
            const bf16x8 kf0 = *(const bf16x8*)&Ks[(nt * 16 + ln) * 72 + quad * 8];
            const bf16x8 kf1 = *(const bf16x8*)&Ks[(nt * 16 + ln) * 72 + 32 + quad * 8];
            f32x4 zz = (f32x4){0.f, 0.f, 0.f, 0.f};
            zz = MFMA_BF16(kf0, qf0, zz);
            zz = MFMA_BF16(kf1, qf1, zz);
            sa[nt] = zz;
        }

        // ---- online softmax: scalar state per lane (q = ln)
        float mx = -1e30f;
#pragma unroll
        for (int nt = 0; nt < 8; ++nt)
#pragma unroll
            for (int r = 0; r < 4; ++r) mx = fmaxf(mx, sa[nt][r]);
        mx = fmaxf(mx, __shfl_xor(mx, 16));
        mx = fmaxf(mx, __shfl_xor(mx, 32));
        const float mn = fmaxf(m_s, mx);
        const float al = exp2f(m_s - mn);
        m_s = mn;
        float rs = 0.f;
#pragma unroll
        for (int nt = 0; nt < 8; ++nt)
#pragma unroll
            for (int r = 0; r < 4; ++r) {
                const float p = exp2f(sa[nt][r] - mn);
                sa[nt][r] = p;
                rs += p;
            }
        rs += __shfl_xor(rs, 16);
        rs += __shfl_xor(rs, 32);
        l_s = l_s * al + rs;

        // rescale o_acc rows (q_local = quad*4+r) by that row's alpha
#pragma unroll
        for (int r = 0; r < 4; ++r) {
            const float alr = __shfl(al, quad * 4 + r);
#pragma unroll
            for (int c = 0; c < 4; ++c) o_acc[c][r] *= alr;
        }

        // ---- P -> Ps[q][k]: 8 conflict-free b64 writes (4 consecutive k)
#pragma unroll
        for (int nt = 0; nt < 8; ++nt) {
            bf16x4 pk = {(bf16)sa[nt][0], (bf16)sa[nt][1],
                         (bf16)sa[nt][2], (bf16)sa[nt][3]};
            *(bf16x4*)&Ps[psrow + nt * 16 + quad * 4] = pk;
        }
        // Ps rows are wave-private: wave-local drain instead of barrier
        __asm__ volatile("s_waitcnt lgkmcnt(0)" ::: "memory");

        // ---- O += P·V  (A from Ps, B from swizzled Vt)
#pragma unroll
        for (int kc = 0; kc < 4; ++kc) {
            const bf16x8 pf = *(const bf16x8*)&Ps[psrow + kc * 32 + quad * 8];
#pragma unroll
            for (int c = 0; c < 4; ++c) {
                const int e = c * 16 + ln;
                const int phys = (kc * 4 + quad) ^ (e >> 3);
                const bf16x8 vf = *(const bf16x8*)&Vt[e * 136 + phys * 8];
                o_acc[c] = MFMA_BF16(pf, vf, o_acc[c]);
            }
        }
    }

    // ---- epilogue: rows q_local = quad*4+r, cols e = c*16+ln
    const float linv = 1.0f / l_s;
#pragma unroll
    for (int r = 0; r < 4; ++r) {
        const float lr = __shfl(linv, quad * 4 + r);
        const size_t rowoff = (size_t)(b * SEQ + q0 + w * 16 + quad * 4 + r) * DIM + h * HDIM;
#pragma unroll
        for (int c = 0; c < 4; ++c)
            O[rowoff + c * 16 + ln] = (bf16)(o_acc[c][r] * lr);
    }
}

extern "C" void kernel_launch(void* const* d_in, const int* in_sizes, int n_in,
                              void* d_out, int out_size, void* d_ws, size_t ws_size,
                              hipStream_t stream) {
    bf16* Qb   = (bf16*)d_ws;
    bf16* Kb   = Qb + (size_t)MROWS * DIM;
    bf16* Vb   = Kb + (size_t)MROWS * DIM;
    bf16* Ob   = Vb + (size_t)MROWS * DIM;
    bf16* OutB = Ob + (size_t)MROWS * DIM;
    bf16* conv = OutB + (size_t)MROWS * DIM;
    int*  flags = (int*)(conv + CONV_TOTAL);

    InPack pack;
    for (int i = 0; i < NIN; ++i) {
        pack.p[i] = d_in[i];
        pack.o[i] = H_OFF[i];
        pack.n[i] = in_sizes[i];
    }

    detect_kernel<<<NIN, 256, 0, stream>>>(pack, flags);
    convert_kernel<<<dim3(1024, NIN), 256, 0, stream>>>(pack, conv, flags);

    const bf16* qc  = conv + H_OFF[0];
    const bf16* kc  = conv + H_OFF[1];
    const bf16* vc  = conv + H_OFF[2];
    const bf16* Wqc = conv + H_OFF[3];
    const bf16* bqc = conv + H_OFF[4];
    const bf16* Wkc = conv + H_OFF[5];
    const bf16* bkc = conv + H_OFF[6];
    const bf16* Wvc = conv + H_OFF[7];
    const bf16* bvc = conv + H_OFF[8];
    const bf16* Woc = conv + H_OFF[9];
    const bf16* boc = conv + H_OFF[10];

    gemm_bt_kernel<<<dim3(DIM / 128, MROWS / 128, 3), 256, 0, stream>>>(
        qc, Wqc, bqc, Qb,  kc, Wkc, bkc, Kb,  vc, Wvc, bvc, Vb);

    attn_kernel<<<dim3(SEQ / 64, BATCH * 16), 256, 0, stream>>>(Qb, Kb, Vb, Ob);

    gemm_bt_kernel<<<dim3(DIM / 128, MROWS / 128, 1), 256, 0, stream>>>(
        Ob, Woc, boc, OutB,  Ob, Woc, boc, OutB,  Ob, Woc, boc, OutB);

    writeback_kernel<<<1024, 256, 0, stream>>>(OutB, d_out, flags, out_size);
}

// Round 5
// 323.901 us; speedup vs baseline: 1.2311x; 1.0295x over previous
//
#include <hip/hip_runtime.h>
#include <stdint.h>

typedef __bf16 bf16;
typedef __bf16 bf16x8 __attribute__((ext_vector_type(8)));  // 16B
typedef __bf16 bf16x4 __attribute__((ext_vector_type(4)));  // 8B
typedef float  f32x4  __attribute__((ext_vector_type(4)));

#define MFMA_BF16(a, b, c) __builtin_amdgcn_mfma_f32_16x16x32_bf16((a), (b), (c), 0, 0, 0)

static constexpr int BATCH = 2;
static constexpr int SEQ   = 2048;
static constexpr int DIM   = 1024;
static constexpr int HDIM  = 64;
static constexpr int MROWS = BATCH * SEQ;   // 4096
static constexpr int NIN   = 11;

static const long long H_OFF[NIN] = {
    0, 4194304, 8388608,                 // q, k, v
    12582912, 13631488,                  // Wq, bq
    13632512, 14681088,                  // Wk, bk
    14682112, 15730688,                  // Wv, bv
    15731712, 16780288                   // Wo, bo
};
static constexpr long long CONV_TOTAL = 16781312;

struct InPack {
    const void* p[NIN];
    long long   o[NIN];
    int         n[NIN];
};

__device__ __forceinline__ float scrubf(float v) {
    unsigned b = __float_as_uint(v);
    return ((b & 0x7f800000u) == 0x7f800000u) ? 0.f : v;  // NaN/Inf -> 0
}

typedef const __attribute__((address_space(1))) void* gvp;
typedef __attribute__((address_space(3))) void* svp;
__device__ __forceinline__ void glds16(const bf16* g, bf16* l) {
    __builtin_amdgcn_global_load_lds((gvp)(const void*)g, (svp)(void*)l, 16, 0, 0);
}

// ---------------------------------------------------------------------------
// dtype detection (fp32 vs bf16), per input buffer. flags[i]=1 -> fp32.
// ---------------------------------------------------------------------------
__global__ void detect_kernel(InPack in, int* __restrict__ flags) {
    const int i = blockIdx.x;
    const unsigned short* s = (const unsigned short*)in.p[i];
    const int scan = in.n[i] < 65536 ? in.n[i] : 65536;
    __shared__ int bad;
    if (threadIdx.x == 0) bad = 0;
    __syncthreads();
    int local = 0;
    for (int j = threadIdx.x; j < scan; j += 256) {
        const int e = (s[j] >> 7) & 0xFF;
        if (e >= 0x89) ++local;
    }
    if (local) atomicAdd(&bad, local);
    __syncthreads();
    if (threadIdx.x == 0) flags[i] = (bad > 0) ? 1 : 0;
}

__global__ void convert_kernel(InPack in, bf16* __restrict__ dstbase,
                               const int* __restrict__ flags) {
    const int i = blockIdx.y;
    const int n4 = in.n[i] >> 2;
    bf16* dst = dstbase + in.o[i];
    const bool isf32 = (flags[i] != 0);
    for (int j = blockIdx.x * 256 + threadIdx.x; j < n4; j += gridDim.x * 256) {
        float v0, v1, v2, v3;
        if (isf32) {
            const float4 f = ((const float4*)in.p[i])[j];
            v0 = f.x; v1 = f.y; v2 = f.z; v3 = f.w;
        } else {
            const ushort4 u = ((const ushort4*)in.p[i])[j];
            v0 = __uint_as_float((unsigned)u.x << 16);
            v1 = __uint_as_float((unsigned)u.y << 16);
            v2 = __uint_as_float((unsigned)u.z << 16);
            v3 = __uint_as_float((unsigned)u.w << 16);
        }
        bf16x4 o = {(bf16)scrubf(v0), (bf16)scrubf(v1), (bf16)scrubf(v2), (bf16)scrubf(v3)};
        *(bf16x4*)&dst[(size_t)j * 4] = o;
    }
}

__global__ void writeback_kernel(const bf16* __restrict__ src, void* __restrict__ out,
                                 const int* __restrict__ flags, int n) {
    const bool f32 = (flags[0] != 0);
    const int n4 = n >> 2;
    for (int j = blockIdx.x * 256 + threadIdx.x; j < n4; j += gridDim.x * 256) {
        const bf16x4 s = *(const bf16x4*)&src[(size_t)j * 4];
        if (f32) {
            float4 f = {(float)s[0], (float)s[1], (float)s[2], (float)s[3]};
            ((float4*)out)[j] = f;
        } else {
            ((bf16x4*)out)[j] = s;
        }
    }
}

// ---------------------------------------------------------------------------
// GEMM: C[M,DIM] = A[M,DIM] @ W[DIM,DIM]^T + bias. 128x128 tile, BK=32,
// global_load_lds(16B) staging into unpadded [row][32] LDS.
// ---------------------------------------------------------------------------
__global__ __launch_bounds__(256, 3) void gemm_bt_kernel(
    const bf16* __restrict__ A0, const bf16* __restrict__ W0,
    const bf16* __restrict__ b0, bf16* __restrict__ C0,
    const bf16* __restrict__ A1, const bf16* __restrict__ W1,
    const bf16* __restrict__ b1, bf16* __restrict__ C1,
    const bf16* __restrict__ A2, const bf16* __restrict__ W2,
    const bf16* __restrict__ b2, bf16* __restrict__ C2)
{
    const int z = blockIdx.z;
    const bf16* A    = (z == 0) ? A0 : (z == 1) ? A1 : A2;
    const bf16* W    = (z == 0) ? W0 : (z == 1) ? W1 : W2;
    const bf16* bias = (z == 0) ? b0 : (z == 1) ? b1 : b2;
    bf16*       C    = (z == 0) ? C0 : (z == 1) ? C1 : C2;

    const int n0 = blockIdx.x * 128;
    const int m0 = blockIdx.y * 128;

    __shared__ bf16 As[128 * 32];
    __shared__ bf16 Bs[128 * 32];

    const int t    = threadIdx.x;
    const int w    = t >> 6;
    const int lane = t & 63;
    const int ln   = t & 15;
    const int quad = (t >> 4) & 3;
    const int wm   = (w & 1) * 64;
    const int wn   = (w >> 1) * 64;

    const int srow = w * 32 + (lane >> 2);
    const int scol = (lane & 3) * 8;
    const bf16* gA = A + (size_t)(m0 + srow) * DIM + scol;
    const bf16* gB = W + (size_t)(n0 + srow) * DIM + scol;
    bf16* lA = &As[w * 32 * 32];
    bf16* lB = &Bs[w * 32 * 32];

    f32x4 acc[4][4];
#pragma unroll
    for (int i = 0; i < 4; ++i)
#pragma unroll
        for (int j = 0; j < 4; ++j) acc[i][j] = (f32x4){0.f, 0.f, 0.f, 0.f};

    for (int k0 = 0; k0 < DIM; k0 += 32) {
        __syncthreads();
        glds16(gA + k0,            lA);
        glds16(gA + 16 * DIM + k0, lA + 16 * 32);
        glds16(gB + k0,            lB);
        glds16(gB + 16 * DIM + k0, lB + 16 * 32);
        __syncthreads();

        bf16x8 af[4], bfr[4];
#pragma unroll
        for (int mt = 0; mt < 4; ++mt)
            af[mt] = *(const bf16x8*)&As[(wm + mt * 16 + ln) * 32 + quad * 8];
#pragma unroll
        for (int nt = 0; nt < 4; ++nt)
            bfr[nt] = *(const bf16x8*)&Bs[(wn + nt * 16 + ln) * 32 + quad * 8];
#pragma unroll
        for (int mt = 0; mt < 4; ++mt)
#pragma unroll
            for (int nt = 0; nt < 4; ++nt)
                acc[mt][nt] = MFMA_BF16(af[mt], bfr[nt], acc[mt][nt]);
    }

#pragma unroll
    for (int nt = 0; nt < 4; ++nt) {
        const int col  = n0 + wn + nt * 16 + ln;
        const float bv = (float)bias[col];
#pragma unroll
        for (int mt = 0; mt < 4; ++mt)
#pragma unroll
            for (int r = 0; r < 4; ++r) {
                const int row = m0 + wm + mt * 16 + quad * 4 + r;
                C[(size_t)row * DIM + col] = (bf16)(acc[mt][nt][r] + bv);
            }
    }
}

// ---------------------------------------------------------------------------
// Flash attention, S^T formulation, BQ=128: block = 128 q-rows of one (b,h),
// wave = 32 q-rows as two 16-row groups g=0,1. K/V fragments loaded ONCE per
// k-tile and reused across both groups. Ps is wave-private [16 rows/wave],
// two-pass (g0 then g1) with wave-local lgkmcnt drains (no extra barriers).
// ---------------------------------------------------------------------------
__global__ __launch_bounds__(256, 2) void attn_kernel(
    const bf16* __restrict__ Q, const bf16* __restrict__ K,
    const bf16* __restrict__ V, bf16* __restrict__ O)
{
    const int qt = blockIdx.x;        // 0..15: 128 q-rows
    const int bh = blockIdx.y;        // 0..31
    const int b  = bh >> 4;
    const int h  = bh & 15;

    __shared__ bf16 Ks[128 * 72];     // [k_row][e], stride 72
    __shared__ bf16 Vt[64 * 136];     // [e][k], stride 136, chunk-swizzled
    __shared__ bf16 Ps[64 * 136];     // 16 rows per wave, reused g0/g1

    const int t    = threadIdx.x;
    const int w    = t >> 6;
    const int lane = t & 63;
    const int ln   = lane & 15;
    const int quad = lane >> 4;

    const int q0 = qt * 128;

    // Q^T B-operand frags for both groups, pre-scaled by 1/sqrt(HD)*log2(e)
    const float sc = 0.125f * 1.44269504089f;
    bf16x8 qf[2][2];
#pragma unroll
    for (int g = 0; g < 2; ++g) {
        const bf16* qrow = Q + (size_t)(b * SEQ + q0 + w * 32 + g * 16 + ln) * DIM + h * HDIM;
        qf[g][0] = *(const bf16x8*)(qrow + quad * 8);
        qf[g][1] = *(const bf16x8*)(qrow + 32 + quad * 8);
#pragma unroll
        for (int i = 0; i < 8; ++i) {
            qf[g][0][i] = (bf16)((float)qf[g][0][i] * sc);
            qf[g][1][i] = (bf16)((float)qf[g][1][i] * sc);
        }
    }

    f32x4 o_acc[2][4];
#pragma unroll
    for (int g = 0; g < 2; ++g)
#pragma unroll
        for (int c = 0; c < 4; ++c) o_acc[g][c] = (f32x4){0.f, 0.f, 0.f, 0.f};
    float m_s[2] = {-1e30f, -1e30f};
    float l_s[2] = {0.f, 0.f};

    const int krow = t >> 3;          // K staging
    const int kcol = (t & 7) * 8;
    const int vrq  = t >> 3;          // V staging
    const int va   = t & 7;
    const int psrow = (w * 16 + ln) * 136;
    const int pswr  = (w * 16) * 136; // wave's Ps base for writes (row = +quad rows via ln)

    for (int kb = 0; kb < SEQ; kb += 128) {
        __syncthreads();
        // ---- stage K [128][64]
#pragma unroll
        for (int i = 0; i < 4; ++i) {
            const int r = krow + i * 32;
            *(bf16x8*)&Ks[r * 72 + kcol] =
                *(const bf16x8*)(K + (size_t)(b * SEQ + kb + r) * DIM + h * HDIM + kcol);
        }
        // ---- stage V^T, XOR-chunk swizzle
        {
            bf16x8 vrow[4];
            const bf16* vbase = V + (size_t)(b * SEQ + kb + vrq * 4) * DIM + h * HDIM + va * 8;
#pragma unroll
            for (int i = 0; i < 4; ++i)
                vrow[i] = *(const bf16x8*)(vbase + (size_t)i * DIM);
            const int phys = ((vrq >> 1) ^ va) * 8 + (vrq & 1) * 4;
#pragma unroll
            for (int j = 0; j < 8; ++j) {
                bf16x4 pk = {vrow[0][j], vrow[1][j], vrow[2][j], vrow[3][j]};
                *(bf16x4*)&Vt[(va * 8 + j) * 136 + phys] = pk;
            }
        }
        __syncthreads();

        // ---- S^T = K·Q^T for both q-groups; K-frags loaded once
        f32x4 sa0[8], sa1[8];
#pragma unroll
        for (int nt = 0; nt < 8; ++nt) {
            const bf16x8 kf0 = *(const bf16x8*)&Ks[(nt * 16 + ln) * 72 + quad * 8];
            const bf16x8 kf1 = *(const bf16x8*)&Ks[(nt * 16 + ln) * 72 + 32 + quad * 8];
            f32x4 z0 = (f32x4){0.f, 0.f, 0.f, 0.f};
            z0 = MFMA_BF16(kf0, qf[0][0], z0);
            z0 = MFMA_BF16(kf1, qf[0][1], z0);
            sa0[nt] = z0;
            f32x4 z1 = (f32x4){0.f, 0.f, 0.f, 0.f};
            z1 = MFMA_BF16(kf0, qf[1][0], z1);
            z1 = MFMA_BF16(kf1, qf[1][1], z1);
            sa1[nt] = z1;
        }

        // ---- online softmax for both groups (scalar state per lane, q=ln)
        float al[2];
#pragma unroll
        for (int g = 0; g < 2; ++g) {
            f32x4* sa = g ? sa1 : sa0;
            float mx = -1e30f;
#pragma unroll
            for (int nt = 0; nt < 8; ++nt)
#pragma unroll
                for (int r = 0; r < 4; ++r) mx = fmaxf(mx, sa[nt][r]);
            mx = fmaxf(mx, __shfl_xor(mx, 16));
            mx = fmaxf(mx, __shfl_xor(mx, 32));
            const float mn = fmaxf(m_s[g], mx);
            al[g] = exp2f(m_s[g] - mn);
            m_s[g] = mn;
            float rs = 0.f;
#pragma unroll
            for (int nt = 0; nt < 8; ++nt)
#pragma unroll
                for (int r = 0; r < 4; ++r) {
                    const float p = exp2f(sa[nt][r] - mn);
                    sa[nt][r] = p;
                    rs += p;
                }
            rs += __shfl_xor(rs, 16);
            rs += __shfl_xor(rs, 32);
            l_s[g] = l_s[g] * al[g] + rs;
            // rescale o_acc rows (q_local = quad*4+r)
#pragma unroll
            for (int r = 0; r < 4; ++r) {
                const float alr = __shfl(al[g], quad * 4 + r);
#pragma unroll
                for (int c = 0; c < 4; ++c) o_acc[g][c][r] *= alr;
            }
        }

        // ---- P g0 -> Ps
#pragma unroll
        for (int nt = 0; nt < 8; ++nt) {
            bf16x4 pk = {(bf16)sa0[nt][0], (bf16)sa0[nt][1],
                         (bf16)sa0[nt][2], (bf16)sa0[nt][3]};
            *(bf16x4*)&Ps[psrow + nt * 16 + quad * 4] = pk;
        }
        __asm__ volatile("s_waitcnt lgkmcnt(0)" ::: "memory");
        // pf g0
        bf16x8 pf0[4];
#pragma unroll
        for (int kc = 0; kc < 4; ++kc)
            pf0[kc] = *(const bf16x8*)&Ps[psrow + kc * 32 + quad * 8];
        __asm__ volatile("s_waitcnt lgkmcnt(0)" ::: "memory");  // reads done before overwrite
        // ---- P g1 -> Ps (same rows)
#pragma unroll
        for (int nt = 0; nt < 8; ++nt) {
            bf16x4 pk = {(bf16)sa1[nt][0], (bf16)sa1[nt][1],
                         (bf16)sa1[nt][2], (bf16)sa1[nt][3]};
            *(bf16x4*)&Ps[psrow + nt * 16 + quad * 4] = pk;
        }
        // ---- V frags, loaded once for both groups
        bf16x8 vf[4][4];
#pragma unroll
        for (int kc = 0; kc < 4; ++kc)
#pragma unroll
            for (int c = 0; c < 4; ++c) {
                const int e = c * 16 + ln;
                const int phys = (kc * 4 + quad) ^ (e >> 3);
                vf[kc][c] = *(const bf16x8*)&Vt[e * 136 + phys * 8];
            }
        __asm__ volatile("s_waitcnt lgkmcnt(0)" ::: "memory");  // g1 writes + vf reads done

        // ---- PV g0
#pragma unroll
        for (int kc = 0; kc < 4; ++kc)
#pragma unroll
            for (int c = 0; c < 4; ++c)
                o_acc[0][c] = MFMA_BF16(pf0[kc], vf[kc][c], o_acc[0][c]);
        // pf g1
        bf16x8 pf1[4];
#pragma unroll
        for (int kc = 0; kc < 4; ++kc)
            pf1[kc] = *(const bf16x8*)&Ps[psrow + kc * 32 + quad * 8];
        __asm__ volatile("s_waitcnt lgkmcnt(0)" ::: "memory");
        // ---- PV g1
#pragma unroll
        for (int kc = 0; kc < 4; ++kc)
#pragma unroll
            for (int c = 0; c < 4; ++c)
                o_acc[1][c] = MFMA_BF16(pf1[kc], vf[kc][c], o_acc[1][c]);
    }

    // ---- epilogue
#pragma unroll
    for (int g = 0; g < 2; ++g) {
        const float linv = 1.0f / l_s[g];
#pragma unroll
        for (int r = 0; r < 4; ++r) {
            const float lr = __shfl(linv, quad * 4 + r);
            const size_t rowoff =
                (size_t)(b * SEQ + q0 + w * 32 + g * 16 + quad * 4 + r) * DIM + h * HDIM;
#pragma unroll
            for (int c = 0; c < 4; ++c)
                O[rowoff + c * 16 + ln] = (bf16)(o_acc[g][c][r] * lr);
        }
    }
}

extern "C" void kernel_launch(void* const* d_in, const int* in_sizes, int n_in,
                              void* d_out, int out_size, void* d_ws, size_t ws_size,
                              hipStream_t stream) {
    bf16* Qb   = (bf16*)d_ws;
    bf16* Kb   = Qb + (size_t)MROWS * DIM;
    bf16* Vb   = Kb + (size_t)MROWS * DIM;
    bf16* Ob   = Vb + (size_t)MROWS * DIM;
    bf16* OutB = Ob + (size_t)MROWS * DIM;
    bf16* conv = OutB + (size_t)MROWS * DIM;
    int*  flags = (int*)(conv + CONV_TOTAL);

    InPack pack;
    for (int i = 0; i < NIN; ++i) {
        pack.p[i] = d_in[i];
        pack.o[i] = H_OFF[i];
        pack.n[i] = in_sizes[i];
    }

    detect_kernel<<<NIN, 256, 0, stream>>>(pack, flags);
    convert_kernel<<<dim3(1024, NIN), 256, 0, stream>>>(pack, conv, flags);

    const bf16* qc  = conv + H_OFF[0];
    const bf16* kc  = conv + H_OFF[1];
    const bf16* vc  = conv + H_OFF[2];
    const bf16* Wqc = conv + H_OFF[3];
    const bf16* bqc = conv + H_OFF[4];
    const bf16* Wkc = conv + H_OFF[5];
    const bf16* bkc = conv + H_OFF[6];
    const bf16* Wvc = conv + H_OFF[7];
    const bf16* bvc = conv + H_OFF[8];
    const bf16* Woc = conv + H_OFF[9];
    const bf16* boc = conv + H_OFF[10];

    gemm_bt_kernel<<<dim3(DIM / 128, MROWS / 128, 3), 256, 0, stream>>>(
        qc, Wqc, bqc, Qb,  kc, Wkc, bkc, Kb,  vc, Wvc, bvc, Vb);

    attn_kernel<<<dim3(SEQ / 128, BATCH * 16), 256, 0, stream>>>(Qb, Kb, Vb, Ob);

    gemm_bt_kernel<<<dim3(DIM / 128, MROWS / 128, 1), 256, 0, stream>>>(
        Ob, Woc, boc, OutB,  Ob, Woc, boc, OutB,  Ob, Woc, boc, OutB);

    writeback_kernel<<<1024, 256, 0, stream>>>(OutB, d_out, flags, out_size);
}